// Round 3
// baseline (30372.620 us; speedup 1.0000x reference)
//
#include <hip/hip_runtime.h>

#define HID  64
#define SEQT 1024

typedef float v2f __attribute__((ext_vector_type(2)));
typedef float v4f __attribute__((ext_vector_type(4)));

__device__ __forceinline__ float rcpf(float x) { return __builtin_amdgcn_rcpf(x); }
__device__ __forceinline__ float sigm(float x) { return rcpf(1.0f + __expf(-x)); }
__device__ __forceinline__ float tanh_fast(float x) {
    // 1 - 2/(e^{2x}+1); correct saturation at +-inf
    return 1.0f - 2.0f * rcpf(__expf(2.0f * x) + 1.0f);
}
__device__ __forceinline__ v2f pkfma(v2f a, v2f b, v2f c) {
    return __builtin_elementwise_fma(a, b, c);   // -> v_pk_fma_f32
}

// One block = TWO batch elements (b0=2*blk, b1=2*blk+1). 256 threads, 4 waves.
// Round-1 layout kept exactly (it register-allocated cleanly): wave w = gate
// type, lane j = unit, thread g = gate row; weights register-resident (96 v2f).
// Each weight v2f now feeds 2 pk_fma (one per batch) -> per-weight issue tax
// amortized 2x, FMA issue halved by v_pk_fma_f32.
// h is stored pair-interleaved per wave: word 4q..4q+3 = {b0.h[2q],b0.h[2q+1],
// b1.h[2q],b1.h[2q+1]} so ONE broadcast ds_read_b128 feeds one pk per batch.
__global__ __launch_bounds__(256, 2)
void lstm2_nb2(const float* __restrict__ x,
               const float* __restrict__ W_ih0, const float* __restrict__ W_hh0,
               const float* __restrict__ b_ih0, const float* __restrict__ b_hh0,
               const float* __restrict__ W_ih1, const float* __restrict__ W_hh1,
               const float* __restrict__ b_ih1, const float* __restrict__ b_hh1,
               const float* __restrict__ fc1_w, const float* __restrict__ fc1_b,
               const float* __restrict__ fc2_w, const float* __restrict__ fc2_b,
               float* __restrict__ out, int nblocks)
{
    const int blk = blockIdx.x;
    if (blk >= nblocks) return;
    const int tid = threadIdx.x;
    const int w   = tid >> 6;     // wave = gate type (0:i 1:f 2:g 3:o)
    const int j   = tid & 63;     // lane = unit
    const int g   = tid;          // gate row 0..255

    __shared__ __align__(16) float gates0[512];      // [gate][batch] -> 2g+b
    __shared__ __align__(16) float gates1[512];
    __shared__ __align__(16) float H1[4][128];       // per-wave replica, pair-interleaved
    __shared__ __align__(16) float H2[4][128];

    // ---- register-resident weight rows, v2f over k ----
    v2f whh0[32], wih1[32], whh1[32];
    {
        const v2f* r0 = (const v2f*)(W_hh0 + g * HID);
        const v2f* r1 = (const v2f*)(W_ih1 + g * HID);
        const v2f* r2 = (const v2f*)(W_hh1 + g * HID);
        #pragma unroll
        for (int q = 0; q < 32; ++q) { whh0[q] = r0[q]; wih1[q] = r1[q]; whh1[q] = r2[q]; }
    }
    const float wih0g = W_ih0[g];                    // INPUT_SIZE == 1
    const float bias0 = b_ih0[g] + b_hh0[g];
    const float bias1 = b_ih1[g] + b_hh1[g];

    v2f c1 = {0.f, 0.f}, c2 = {0.f, 0.f};            // .x=b0, .y=b1
    H1[w][j] = 0.f; H1[w][64 + j] = 0.f;
    H2[w][j] = 0.f; H2[w][64 + j] = 0.f;
    __syncthreads();

    const float* __restrict__ x0 = x + (size_t)(2 * blk) * SEQT;
    const float* __restrict__ x1 = x0 + SEQT;
    float* __restrict__ H1w = H1[w];
    float* __restrict__ H2w = H2[w];
    const v4f* __restrict__ h1v = (const v4f*)H1w;   // 32 v4f: one k-pair, both batches
    const v4f* __restrict__ h2v = (const v4f*)H2w;
    const int p  = 4 * (j >> 1) + (j & 1);           // interleaved slot of unit j, b0
    // b1 slot = p + 2

    for (int t0 = 0; t0 < SEQT; t0 += 64) {
        const float xc0 = x0[t0 + j];
        const float xc1 = x1[t0 + j];
        #pragma unroll 1
        for (int tt = 0; tt < 64; ++tt) {
            const float xt0 = __shfl(xc0, tt);
            const float xt1 = __shfl(xc1, tt);

            // ---------- layer 0 gates: 32 reads, 64 pk ----------
            v2f a00 = {0.f,0.f}, a01 = {0.f,0.f};    // b0, two chains
            v2f a10 = {0.f,0.f}, a11 = {0.f,0.f};    // b1
            #pragma unroll
            for (int q = 0; q < 32; q += 2) {
                v4f ha = h1v[q], hb = h1v[q + 1];
                v2f alo = {ha.x, ha.y}, ahi = {ha.z, ha.w};
                v2f blo = {hb.x, hb.y}, bhi = {hb.z, hb.w};
                a00 = pkfma(alo, whh0[q],     a00);
                a10 = pkfma(ahi, whh0[q],     a10);
                a01 = pkfma(blo, whh0[q + 1], a01);
                a11 = pkfma(bhi, whh0[q + 1], a11);
            }
            v2f s0 = a00 + a01, s1 = a10 + a11;
            float pre00 = fmaf(xt0, wih0g, bias0) + (s0.x + s0.y);
            float pre01 = fmaf(xt1, wih0g, bias0) + (s1.x + s1.y);
            float act00 = (w == 2) ? tanh_fast(pre00) : sigm(pre00);
            float act01 = (w == 2) ? tanh_fast(pre01) : sigm(pre01);
            *(v2f*)&gates0[2 * g] = (v2f){act00, act01};
            __syncthreads();

            // ---------- layer 0 cell update (per-wave replica) ----------
            {
                v2f i0 = *(const v2f*)&gates0[2 * j];
                v2f f0 = *(const v2f*)&gates0[2 * (64 + j)];
                v2f g0 = *(const v2f*)&gates0[2 * (128 + j)];
                v2f o0 = *(const v2f*)&gates0[2 * (192 + j)];
                c1 = pkfma(f0, c1, i0 * g0);
                v2f th; th.x = tanh_fast(c1.x); th.y = tanh_fast(c1.y);
                v2f h1n = o0 * th;
                H1w[p]     = h1n.x;
                H1w[p + 2] = h1n.y;
            }
            // within-wave write->read: lgkmcnt ordering, no barrier needed

            // ---------- layer 1 gates: 64 reads, 128 pk ----------
            v2f bA = {0.f,0.f}, bB = {0.f,0.f};      // b0: h1-chain, h2-chain
            v2f bC = {0.f,0.f}, bD = {0.f,0.f};      // b1
            #pragma unroll
            for (int q = 0; q < 32; ++q) {
                v4f u = h1v[q], v = h2v[q];
                v2f ulo = {u.x, u.y}, uhi = {u.z, u.w};
                v2f vlo = {v.x, v.y}, vhi = {v.z, v.w};
                bA = pkfma(ulo, wih1[q], bA);
                bB = pkfma(vlo, whh1[q], bB);
                bC = pkfma(uhi, wih1[q], bC);
                bD = pkfma(vhi, whh1[q], bD);
            }
            v2f sb0 = bA + bB, sb1 = bC + bD;
            float pre10 = bias1 + (sb0.x + sb0.y);
            float pre11 = bias1 + (sb1.x + sb1.y);
            float act10 = (w == 2) ? tanh_fast(pre10) : sigm(pre10);
            float act11 = (w == 2) ? tanh_fast(pre11) : sigm(pre11);
            *(v2f*)&gates1[2 * g] = (v2f){act10, act11};
            __syncthreads();

            // ---------- layer 1 cell update ----------
            {
                v2f i1 = *(const v2f*)&gates1[2 * j];
                v2f f1 = *(const v2f*)&gates1[2 * (64 + j)];
                v2f g1 = *(const v2f*)&gates1[2 * (128 + j)];
                v2f o1 = *(const v2f*)&gates1[2 * (192 + j)];
                c2 = pkfma(f1, c2, i1 * g1);
                v2f th; th.x = tanh_fast(c2.x); th.y = tanh_fast(c2.y);
                v2f h2n = o1 * th;
                H2w[p]     = h2n.x;
                H2w[p + 2] = h2n.y;
            }
        }
    }

    // ---------- FC head: wave 0 -> b0, wave 1 -> b1 (own H2 replica) ----------
    if (w < 2) {
        float z = 0.0f;
        if (j < 32) {
            float acc = fc1_b[j];
            #pragma unroll
            for (int k = 0; k < HID; ++k) {
                float h = H2w[4 * (k >> 1) + 2 * w + (k & 1)];
                acc = fmaf(h, fc1_w[j * HID + k], acc);
            }
            z = fmaxf(acc, 0.0f) * fc2_w[j];
        }
        #pragma unroll
        for (int off = 32; off > 0; off >>= 1) z += __shfl_xor(z, off);
        if (j == 0) out[2 * blk + w] = z + fc2_b[0];
    }
}

extern "C" void kernel_launch(void* const* d_in, const int* in_sizes, int n_in,
                              void* d_out, int out_size, void* d_ws, size_t ws_size,
                              hipStream_t stream) {
    const float* x     = (const float*)d_in[0];
    const float* W_ih0 = (const float*)d_in[1];
    const float* W_hh0 = (const float*)d_in[2];
    const float* b_ih0 = (const float*)d_in[3];
    const float* b_hh0 = (const float*)d_in[4];
    const float* W_ih1 = (const float*)d_in[5];
    const float* W_hh1 = (const float*)d_in[6];
    const float* b_ih1 = (const float*)d_in[7];
    const float* b_hh1 = (const float*)d_in[8];
    const float* fc1_w = (const float*)d_in[9];
    const float* fc1_b = (const float*)d_in[10];
    const float* fc2_w = (const float*)d_in[11];
    const float* fc2_b = (const float*)d_in[12];
    float* out = (float*)d_out;

    const int batch   = in_sizes[0] / SEQT;   // 1024
    const int nblocks = batch / 2;            // 512: exactly 2 blocks/CU resident
    dim3 grid(nblocks), block(256);
    hipLaunchKernelGGL(lstm2_nb2, grid, block, 0, stream,
                       x, W_ih0, W_hh0, b_ih0, b_hh0,
                       W_ih1, W_hh1, b_ih1, b_hh1,
                       fc1_w, fc1_b, fc2_w, fc2_b, out, nblocks);
}

// Round 4
// 2153.744 us; speedup vs baseline: 14.1022x; 14.1022x over previous
//
#include <hip/hip_runtime.h>

#define HID  64
#define SEQT 1024

typedef float v2f __attribute__((ext_vector_type(2)));
typedef float v4f __attribute__((ext_vector_type(4)));

__device__ __forceinline__ float rcpf(float x){ return __builtin_amdgcn_rcpf(x); }
__device__ __forceinline__ float sigm(float x){ return rcpf(1.0f + __expf(-x)); }
__device__ __forceinline__ float tanh_fast(float x){
    // 1 - 2/(e^{2x}+1); correct saturation at +-inf
    return 1.0f - 2.0f * rcpf(__expf(2.0f * x) + 1.0f);
}
__device__ __forceinline__ v2f pkfma(v2f a, v2f b, v2f c){
    return __builtin_elementwise_fma(a, b, c);      // -> v_pk_fma_f32
}

// 12 waves (768 thr), block = 2 batch elements (b0,b1).
//   waves 0-3  : L0 gate rows 64w+j for BOTH batches (u=h1[b0], v=h1[b1],
//                wA==wB== W_hh0 row -> only 64 unique weight floats)
//   waves 4-7  : L1 gates, batch b0 (u-chain wih1*h1[b0], v-chain whh1*h2[b0])
//   waves 8-11 : L1 gates, batch b1
// Pipeline: iter k -> L0 emits step k, L1 emits step k-1 (single-buffered H ok
// with 2 barriers). Cell updates: w4=(L0,b0) w5=(L0,b1) w6=(L1,b0) w7=(L1,b1).
// Unified hot-loop body for all waves (no divergent code -> clean regalloc);
// weights <=128 floats/wave, pinned live with empty asm (anti-remat).
__global__ __launch_bounds__(768, 3)
void lstm2_w12(const float* __restrict__ x,
               const float* __restrict__ W_ih0, const float* __restrict__ W_hh0,
               const float* __restrict__ b_ih0, const float* __restrict__ b_hh0,
               const float* __restrict__ W_ih1, const float* __restrict__ W_hh1,
               const float* __restrict__ b_ih1, const float* __restrict__ b_hh1,
               const float* __restrict__ fc1_w, const float* __restrict__ fc1_b,
               const float* __restrict__ fc2_w, const float* __restrict__ fc2_b,
               float* __restrict__ out, int nblk)
{
    const int blk = blockIdx.x;
    if (blk >= nblk) return;
    const int tid   = threadIdx.x;
    const int w     = tid >> 6;          // wave 0..11
    const int j     = tid & 63;          // lane
    const int gtype = w & 3;             // 0:i 1:f 2:g(tanh) 3:o
    const int g     = (gtype << 6) | j;  // gate row within the layer

    __shared__ float gates0[2][256];                 // [batch][gate]
    __shared__ float gates1[2][256];
    __shared__ __align__(16) float H1[2][HID];       // h1 per batch
    __shared__ __align__(16) float H2[2][HID];       // h2 per batch

    // ---------------- role setup (pre-loop, wave-uniform) ----------------
    const float* wrowA;
    const float* wrowB;
    const float* uvp;
    const float* vvp;
    float biasS, wx;
    if (w < 4) {          // L0 dual-batch
        wrowA = W_hh0 + g * HID;  wrowB = wrowA;
        uvp = H1[0];              vvp = H1[1];
        biasS = b_ih0[g] + b_hh0[g];
        wx    = W_ih0[g];                       // INPUT_SIZE == 1
    } else if (w < 8) {   // L1, b0
        wrowA = W_ih1 + g * HID;  wrowB = W_hh1 + g * HID;
        uvp = H1[0];              vvp = H2[0];
        biasS = b_ih1[g] + b_hh1[g];
        wx    = 0.0f;
    } else {              // L1, b1
        wrowA = W_ih1 + g * HID;  wrowB = W_hh1 + g * HID;
        uvp = H1[1];              vvp = H2[1];
        biasS = b_ih1[g] + b_hh1[g];
        wx    = 0.0f;
    }
    float* const g1out = gates1[(w >= 8) ? 1 : 0];   // L1 act output row

    // cell-update role (waves 4..7)
    const bool is_cell = (w >= 4 && w < 8);
    const bool cl1     = (w >= 6);                   // L1 cell vs L0 cell
    const int  cb      = w & 1;                      // batch
    const float* cgate = cl1 ? gates1[cb] : gates0[cb];
    float* const chout = cl1 ? H2[cb] : H1[cb];

    // ---------------- register-resident weights (64 v2f = 128 fl) --------
    v2f wA[32], wB[32];
    {
        const v2f* rA = (const v2f*)wrowA;
        const v2f* rB = (const v2f*)wrowB;
        #pragma unroll
        for (int q = 0; q < 32; ++q) { wA[q] = rA[q]; wB[q] = rB[q]; }
        #pragma unroll
        for (int q = 0; q < 32; ++q) {
            asm volatile("" : "+v"(wA[q]));          // pin live: no remat/reload
            asm volatile("" : "+v"(wB[q]));
        }
    }

    float c = 0.0f;                                  // cell state (waves 4-7)
    if (tid < 128)      ((float*)H1)[tid] = 0.0f;
    else if (tid < 256) ((float*)H2)[tid - 128] = 0.0f;
    __syncthreads();

    const float* __restrict__ x0 = x + (size_t)(2 * blk) * SEQT;
    const float* __restrict__ x1 = x0 + SEQT;
    const v4f* __restrict__ uv = (const v4f*)uvp;
    const v4f* __restrict__ vv = (const v4f*)vvp;

    #define DOT_BODY()                                          \
        v2f a0={0.f,0.f}, a1={0.f,0.f}, a2={0.f,0.f}, a3={0.f,0.f}; \
        _Pragma("unroll")                                       \
        for (int q = 0; q < 16; ++q) {                          \
            v4f u = uv[q], v = vv[q];                           \
            a0 = pkfma((v2f){u.x,u.y}, wA[2*q],   a0);          \
            a1 = pkfma((v2f){u.z,u.w}, wA[2*q+1], a1);          \
            a2 = pkfma((v2f){v.x,v.y}, wB[2*q],   a2);          \
            a3 = pkfma((v2f){v.z,v.w}, wB[2*q+1], a3);          \
        }                                                       \
        v2f s01 = a0 + a1, s23 = a2 + a3;                       \
        float sum01 = s01.x + s01.y, sum23 = s23.x + s23.y;

    // ---------------- main loop: iters k = 0 .. SEQT-1 --------------------
    for (int t0 = 0; t0 < SEQT; t0 += 64) {
        float xc0 = 0.f, xc1 = 0.f;
        if (w < 4) { xc0 = x0[t0 + j]; xc1 = x1[t0 + j]; }  // 64-step prefetch
        #pragma unroll 1
        for (int tt = 0; tt < 64; ++tt) {
            const int k = t0 + tt;

            // -------- phase A: gate dots (all waves, unified body) --------
            { DOT_BODY()
              if (w < 4) {
                  const float xt0 = __shfl(xc0, tt);
                  const float xt1 = __shfl(xc1, tt);
                  float pre0 = fmaf(xt0, wx, biasS) + sum01;
                  float pre1 = fmaf(xt1, wx, biasS) + sum23;
                  gates0[0][g] = (gtype == 2) ? tanh_fast(pre0) : sigm(pre0);
                  gates0[1][g] = (gtype == 2) ? tanh_fast(pre1) : sigm(pre1);
              } else {
                  float pre = biasS + (sum01 + sum23);
                  g1out[g]  = (gtype == 2) ? tanh_fast(pre) : sigm(pre);
              }
            }
            __syncthreads();

            // -------- phase B: cell updates (waves 4-7) -------------------
            if (is_cell && !(cl1 && k == 0)) {
                float iv = cgate[j],        fv = cgate[64 + j];
                float gv = cgate[128 + j],  ov = cgate[192 + j];
                c = fmaf(fv, c, iv * gv);
                chout[j] = ov * tanh_fast(c);
            }
            __syncthreads();
        }
    }

    // ---------------- epilogue iter k = SEQT: last L1 step ----------------
    if (w >= 4) {
        DOT_BODY()
        float pre = biasS + (sum01 + sum23);
        g1out[g]  = (gtype == 2) ? tanh_fast(pre) : sigm(pre);
    }
    __syncthreads();
    if (is_cell && cl1) {
        float iv = cgate[j],        fv = cgate[64 + j];
        float gv = cgate[128 + j],  ov = cgate[192 + j];
        c = fmaf(fv, c, iv * gv);
        chout[j] = ov * tanh_fast(c);
    }
    __syncthreads();

    // ---------------- FC head: wave0 -> b0, wave1 -> b1 -------------------
    if (w < 2) {
        const float* h2last = H2[w];
        float z = 0.0f;
        if (j < 32) {
            float acc = fc1_b[j];
            #pragma unroll
            for (int kk = 0; kk < HID; ++kk)
                acc = fmaf(h2last[kk], fc1_w[j * HID + kk], acc);
            z = fmaxf(acc, 0.0f) * fc2_w[j];
        }
        #pragma unroll
        for (int off = 32; off > 0; off >>= 1) z += __shfl_xor(z, off);
        if (j == 0) out[2 * blk + w] = z + fc2_b[0];
    }
    #undef DOT_BODY
}

extern "C" void kernel_launch(void* const* d_in, const int* in_sizes, int n_in,
                              void* d_out, int out_size, void* d_ws, size_t ws_size,
                              hipStream_t stream) {
    const float* x     = (const float*)d_in[0];
    const float* W_ih0 = (const float*)d_in[1];
    const float* W_hh0 = (const float*)d_in[2];
    const float* b_ih0 = (const float*)d_in[3];
    const float* b_hh0 = (const float*)d_in[4];
    const float* W_ih1 = (const float*)d_in[5];
    const float* W_hh1 = (const float*)d_in[6];
    const float* b_ih1 = (const float*)d_in[7];
    const float* b_hh1 = (const float*)d_in[8];
    const float* fc1_w = (const float*)d_in[9];
    const float* fc1_b = (const float*)d_in[10];
    const float* fc2_w = (const float*)d_in[11];
    const float* fc2_b = (const float*)d_in[12];
    float* out = (float*)d_out;

    const int batch = in_sizes[0] / SEQT;   // 1024
    const int nblk  = batch / 2;            // 512 blocks, 1 block/CU, 2 rounds
    dim3 grid(nblk), block(768);
    hipLaunchKernelGGL(lstm2_w12, grid, block, 0, stream,
                       x, W_ih0, W_hh0, b_ih0, b_hh0,
                       W_ih1, W_hh1, b_ih1, b_hh1,
                       fc1_w, fc1_b, fc2_w, fc2_b, out, nblk);
}